// Round 9
// baseline (136.544 us; speedup 1.0000x reference)
//
#include <hip/hip_runtime.h>

// IndRNN forward: proj = x @ W + b  (M=B*T, K=D=256, N=U), then
// h_t = relu(proj_t + h_{t-1} * clip(u,0,1)) over T.
// R6: bf16 pre-convert + fused: 118.7 total. R8: single launch, fp32 x via
//   gl_lds: fused 60 us. R9: GN=256 regressed (half CUs idle + VGPR spill).
// R10: dbuf Xs + top-of-loop staging issue + counted tail drain: fused 44 us.
//   PMC: VALUBusy 11%, MfmaUtil 6.5%, staging rate 3 TB/s << 9 TB/s L3
//   -> NOT bandwidth-bound; latency-exposure-bound at 1 wave/SIMD.
// R11: 512-THREAD BLOCK (8 waves = 2 waves/SIMD), same structure & grid
//   (256 blocks, full chip). Per-wave tile halves to 16t x 64u (32 MFMA,
//   bfr[4][8]=128 VGPR -> ~190 total, under the 256 limit for 2 waves/SIMD).
//   MFMA phase now co-schedules 2 waves/SIMD (ds_read + MFMA latency hidden);
//   staging spread over 8 waves. Scan stays on waves 0-1; counted drains:
//   scan waves vmcnt(48) (queue [<=48 old stores][8 gl_lds][64 new stores]:
//   retiring to 48 retires >= S+24 oldest >= all gl_lds; S'<=48 induction),
//   others vmcnt(0) (only 8 gl_lds outstanding).

typedef __bf16 bf16x8 __attribute__((ext_vector_type(8)));
typedef float f32x4 __attribute__((ext_vector_type(4)));

typedef const unsigned char __attribute__((address_space(1))) gc_t;
typedef unsigned char __attribute__((address_space(3))) lds_t;

__device__ __forceinline__ void gl_lds16(const void* g, void* l) {
    __builtin_amdgcn_global_load_lds((gc_t*)g, (lds_t*)l, 16, 0, 0);
}

__device__ __forceinline__ bf16x8 cvt8(f32x4 lo, f32x4 hi) {
    bf16x8 r;
    r[0] = (__bf16)lo[0]; r[1] = (__bf16)lo[1];
    r[2] = (__bf16)lo[2]; r[3] = (__bf16)lo[3];
    r[4] = (__bf16)hi[0]; r[5] = (__bf16)hi[1];
    r[6] = (__bf16)hi[2]; r[7] = (__bf16)hi[3];
    return r;
}

// ------------------------------------------------------------ fused kernel
// Requires D == 256, U % 128 == 0, T % 64 == 0.
#define TC 64    // timesteps per chunk
#define GN 128   // units per block

__global__ __launch_bounds__(512, 1) void indrnn_fused(
    const float* __restrict__ x,             // fp32 [B*T, 256]
    const float* __restrict__ W,             // fp32 [256, U]
    const float* __restrict__ bias,          // [U]
    const float* __restrict__ h0,            // [B, U]
    const float* __restrict__ uvec,          // [U]
    float* __restrict__ out,                 // [B, T, U]
    int B, int T, int U)
{
    __shared__ char Xs[2][TC * 1024];        // 2 x 64 KB: fp32 A-chunks (dbuf)
    __shared__ char Ps[GN * TC * 4];         // 32 KB: fp32 proj, transposed [u][t]

    const int tid  = threadIdx.x;
    const int lane = tid & 63;
    const int w    = tid >> 6;     // wave 0..7
    const int m    = lane & 15;
    const int quad = lane >> 4;    // 0..3
    const int b    = blockIdx.x;
    const int n0   = blockIdx.y * GN;
    const int rq   = (w >> 1) * 16;   // wave's 16-row group (t-local): 0/16/32/48
    const int cq   = (w & 1) * 64;    // wave's col half: 0 or 64

    const float* xrow = x + (long)b * T * 256;

    // ---- prologue part 1: stage chunk 0 as fp32 (8 waves, 8 rows each).
    // One gl_lds16 per row: 64 lanes x 16B = 1024 B = full row. LDS granule
    // l <- global granule (l ^ (row&15)).
#pragma unroll
    for (int i = 0; i < 8; ++i) {
        int row = i * 8 + w;
        int sg  = lane ^ (row & 15);
        gl_lds16(xrow + (long)row * 256 + sg * 4, &Xs[0][row * 1024]);
    }

    // ---- prologue part 2 (overlaps DMA): W fragments from fp32 W.
    // bfr[j][kt][e] = bf16( W[(kt*32 + quad*8 + e)][n0 + cq + j*16 + m] ).
    bf16x8 bfr[4][8];
#pragma unroll
    for (int j = 0; j < 4; ++j)
#pragma unroll
        for (int kt = 0; kt < 8; ++kt) {
            const float* wp = W + (long)(kt * 32 + quad * 8) * U
                                + (n0 + cq + j * 16 + m);
            bf16x8 f;
#pragma unroll
            for (int e = 0; e < 8; ++e) f[e] = (__bf16)wp[(long)e * U];
            bfr[j][kt] = f;
        }

    float bb[4];
#pragma unroll
    for (int j = 0; j < 4; ++j) bb[j] = bias[n0 + cq + j * 16 + m];

    float uc = 0.0f, h = 0.0f;
    if (tid < GN) {
        uc = fminf(fmaxf(uvec[n0 + tid], 0.0f), 1.0f);
        h  = h0[(long)b * U + n0 + tid];
    }

    asm volatile("s_waitcnt vmcnt(0)" ::: "memory");
    __builtin_amdgcn_sched_barrier(0);
    __syncthreads();   // chunk 0 staged & visible

    const int nch = T / TC;
    for (int c = 0; c < nch; ++c) {
        const int buf = c & 1;

        // ---- issue staging of chunk c+1 into Xs[buf^1] FIRST: the DMA
        // overlaps this chunk's MFMA+proj+scan. Safe: Xs[buf^1] was last
        // read by MFMA(c-1), ordered by the tail barrier of c-1.
        if (c + 1 < nch) {
            const float* gb = xrow + (long)(c + 1) * TC * 256;
#pragma unroll
            for (int i = 0; i < 8; ++i) {
                int row = i * 8 + w;
                int sg  = lane ^ (row & 15);
                gl_lds16(gb + (long)row * 256 + sg * 4, &Xs[buf ^ 1][row * 1024]);
            }
        }

        // ---- MFMA: wave computes 16t x 64u tile; A read fp32 from LDS,
        //      converted to bf16 in-register (pipelined across kt).
        f32x4 acc[4];
#pragma unroll
        for (int j = 0; j < 4; ++j) acc[j] = (f32x4){0.f, 0.f, 0.f, 0.f};

#pragma unroll
        for (int kt = 0; kt < 8; ++kt) {
            // granule index G = kt*8 | quad*2 | half (disjoint bit fields);
            // LDS granule actually read = G ^ m  (m == row&15).
            const int g0 = ((kt * 8 + quad * 2 + 0) ^ m) << 4;
            const int g1 = ((kt * 8 + quad * 2 + 1) ^ m) << 4;
            const char* rp = Xs[buf] + (rq + m) * 1024;
            f32x4 alo = *(const f32x4*)(rp + g0);
            f32x4 ahi = *(const f32x4*)(rp + g1);
            bf16x8 a = cvt8(alo, ahi);
#pragma unroll
            for (int j = 0; j < 4; ++j)
                acc[j] = __builtin_amdgcn_mfma_f32_16x16x32_bf16(
                    a, bfr[j][kt], acc[j], 0, 0, 0);
        }

        // ---- proj (+bias) -> P, transposed [u][t], 16B-granule XOR swizzle.
#pragma unroll
        for (int j = 0; j < 4; ++j) {
            f32x4 v = acc[j];
            f32x4 vb = {v[0] + bb[j], v[1] + bb[j], v[2] + bb[j], v[3] + bb[j]};
            int col = cq + j * 16 + m;
            int g   = (rq >> 2) + quad;    // (t-row)>>2, t-row = rq + quad*4
            *(f32x4*)(Ps + col * 256 + (((g ^ (col & 7)) << 4))) = vb;
        }
        __syncthreads();   // proj visible to scan waves

        // ---- waves 0-1: sequential scan of chunk c from P (b128 reads)
        if (tid < GN) {
            f32x4 pv[16];
            const int ub = tid * 256;
            const int ux = (tid & 7) << 4;
#pragma unroll
            for (int gg = 0; gg < 16; ++gg)
                pv[gg] = *(const f32x4*)(Ps + ub + ((gg << 4) ^ ux));
            float* og = out + ((long)b * T + c * TC) * U + n0 + tid;
#pragma unroll
            for (int gg = 0; gg < 16; ++gg)
#pragma unroll
                for (int e = 0; e < 4; ++e) {
                    h = fmaxf(fmaf(h, uc, pv[gg][e]), 0.0f);
                    og[(long)(gg * 4 + e) * U] = h;
                }
        }

        // ---- counted tail drain (T4: never blanket vmcnt(0) in-loop).
        // Waves 0-1: queue = [<=48 old stores][8 gl_lds][64 new stores];
        //   vmcnt(48) retires >= S+24 oldest => all gl_lds done; <=48 left.
        // Waves 2-7: only the 8 gl_lds outstanding -> vmcnt(0).
        if (tid < GN) {
            asm volatile("s_waitcnt vmcnt(48)" ::: "memory");
        } else {
            asm volatile("s_waitcnt vmcnt(0)" ::: "memory");
        }
        __builtin_amdgcn_sched_barrier(0);
        __syncthreads();   // chunk c+1 staged; P free for next proj
    }
}

// ------------------------------------------------------------ fp32 fallback
#define BM 128
#define BN 128
#define BK 8

__global__ __launch_bounds__(256) void indrnn_gemm_bias(
    const float* __restrict__ A, const float* __restrict__ Bm,
    const float* __restrict__ bias, float* __restrict__ C,
    int M, int N, int K)
{
    __shared__ float As[BK][BM];
    __shared__ float Bs[BK][BN];
    const int tid = threadIdx.x;
    const int row0 = blockIdx.x * BM, col0 = blockIdx.y * BN;
    const int tx = tid & 15, ty = tid >> 4;
    float acc[8][8];
#pragma unroll
    for (int i = 0; i < 8; ++i)
#pragma unroll
        for (int j = 0; j < 8; ++j) acc[i][j] = 0.0f;
    const int am = tid >> 1, ak = (tid & 1) * 4;
    const int bk = tid >> 5, bn = (tid & 31) * 4;
    const float* Aptr = A + (long)(row0 + am) * K + ak;
    const float* Bptr = Bm + (long)bk * N + col0 + bn;
    for (int kt = 0; kt < K; kt += BK) {
        float4 av = *(const float4*)(Aptr + kt);
        float4 bv = *(const float4*)(Bptr + (long)kt * N);
        As[ak + 0][am] = av.x; As[ak + 1][am] = av.y;
        As[ak + 2][am] = av.z; As[ak + 3][am] = av.w;
        *(float4*)&Bs[bk][bn] = bv;
        __syncthreads();
#pragma unroll
        for (int k = 0; k < BK; ++k) {
            float4 a0 = *(const float4*)&As[k][ty * 4];
            float4 a1 = *(const float4*)&As[k][64 + ty * 4];
            float4 b0 = *(const float4*)&Bs[k][tx * 4];
            float4 b1 = *(const float4*)&Bs[k][64 + tx * 4];
            float a[8] = {a0.x, a0.y, a0.z, a0.w, a1.x, a1.y, a1.z, a1.w};
            float bb2[8] = {b0.x, b0.y, b0.z, b0.w, b1.x, b1.y, b1.z, b1.w};
#pragma unroll
            for (int i = 0; i < 8; ++i)
#pragma unroll
                for (int j = 0; j < 8; ++j)
                    acc[i][j] = fmaf(a[i], bb2[j], acc[i][j]);
        }
        __syncthreads();
    }
    float bb[8];
#pragma unroll
    for (int j = 0; j < 4; ++j) {
        bb[j] = bias[col0 + tx * 4 + j];
        bb[j + 4] = bias[col0 + 64 + tx * 4 + j];
    }
#pragma unroll
    for (int i = 0; i < 8; ++i) {
        const int r = (i < 4) ? (ty * 4 + i) : (64 + ty * 4 + (i - 4));
        float* crow = C + (long)(row0 + r) * N + col0;
        float4 v0 = {acc[i][0] + bb[0], acc[i][1] + bb[1], acc[i][2] + bb[2], acc[i][3] + bb[3]};
        float4 v1 = {acc[i][4] + bb[4], acc[i][5] + bb[5], acc[i][6] + bb[6], acc[i][7] + bb[7]};
        *(float4*)(crow + tx * 4) = v0;
        *(float4*)(crow + 64 + tx * 4) = v1;
    }
}

#define SCAN_UNROLL 32

__global__ __launch_bounds__(256) void indrnn_scan(
    float* __restrict__ out, const float* __restrict__ h0,
    const float* __restrict__ u, int B, int T, int U)
{
    const int idx = blockIdx.x * blockDim.x + threadIdx.x;
    if (idx >= B * U) return;
    const int b = idx / U;
    const int un = idx - b * U;
    const float uc = fminf(fmaxf(u[un], 0.0f), 1.0f);
    float h = h0[(long)b * U + un];
    float* p = out + (long)b * T * U + un;
    for (int t = 0; t < T; t += SCAN_UNROLL) {
        float pv[SCAN_UNROLL];
#pragma unroll
        for (int i = 0; i < SCAN_UNROLL; ++i)
            pv[i] = p[(long)(t + i) * U];
#pragma unroll
        for (int i = 0; i < SCAN_UNROLL; ++i) {
            h = fmaxf(fmaf(h, uc, pv[i]), 0.0f);
            pv[i] = h;
        }
#pragma unroll
        for (int i = 0; i < SCAN_UNROLL; ++i)
            p[(long)(t + i) * U] = pv[i];
    }
}

// ------------------------------------------------------------ launch
extern "C" void kernel_launch(void* const* d_in, const int* in_sizes, int n_in,
                              void* d_out, int out_size, void* d_ws, size_t ws_size,
                              hipStream_t stream) {
    const float* x  = (const float*)d_in[0]; // [B,T,D]
    const float* h0 = (const float*)d_in[1]; // [B,U]
    const float* W  = (const float*)d_in[2]; // [D,U]
    const float* u  = (const float*)d_in[3]; // [U]
    const float* b  = (const float*)d_in[4]; // [U]
    float* out = (float*)d_out;              // [B,T,U]

    const int U = in_sizes[3];
    const int B = in_sizes[1] / U;
    const int D = in_sizes[2] / U;
    const int T = in_sizes[0] / (B * D);
    const int M = B * T;

    const bool fused_ok = (D == 256) && (U % GN == 0) && (T % TC == 0);

    if (fused_ok) {
        dim3 g(B, U / GN);
        indrnn_fused<<<g, 512, 0, stream>>>(x, W, b, h0, u, out, B, T, U);
    } else {
        dim3 ggrid(M / BM, U / BN);
        indrnn_gemm_bias<<<ggrid, 256, 0, stream>>>(x, W, b, out, M, U, D);
        const int nthreads = B * U;
        indrnn_scan<<<(nthreads + 255) / 256, 256, 0, stream>>>(out, h0, u, B, T, U);
    }
}

// Round 10
// 117.173 us; speedup vs baseline: 1.1653x; 1.1653x over previous
//
#include <hip/hip_runtime.h>

// IndRNN forward: proj = x @ W + b  (M=B*T, K=D=256, N=U), then
// h_t = relu(proj_t + h_{t-1} * clip(u,0,1)) over T.
// Evidence model (R6/R8/R9/R10): fused time ~= staged bytes / ~11.5 TB/s
//   (gl_lds staging-path ceiling) + schedule slop. R6 bf16 staging (268 MB):
//   ~25 us. R8/R10 fp32 staging (536 MB): 60/44 us. R10's fixes (dbuf Xs,
//   top-of-loop staging issue, counted tail drains) cut the slop.
// R11 (512 threads): compiler capped VGPR at 128 -> bfr spilled to scratch
//   (FETCH 18.6->27 MB, WRITE 65->85 MB), fused 62 us. REVERTED to 256 thr.
// R12: bf16 staging + R10 schedule composed:
//   - conv_x pre-converts x to bf16 (reads L3-resident x, ~8-9 us);
//   - fused stages bf16 rows via gl_lds (2 x 32 KB dbuf, 96 KB LDS total);
//   - A-frags read directly as bf16x8 (no cvt VALU);
//   - W-frags converted from fp32 W in the prologue (no conv_wt kernel);
//   - counted tail drains: scan waves vmcnt(48), others vmcnt(0).

__device__ __forceinline__ unsigned short f2bf(float f) {
    unsigned int u = __float_as_uint(f);
    unsigned int r = (u + 0x7FFF + ((u >> 16) & 1)) >> 16;  // RNE
    return (unsigned short)r;
}

typedef __bf16 bf16x8 __attribute__((ext_vector_type(8)));
typedef float f32x4 __attribute__((ext_vector_type(4)));

typedef const unsigned char __attribute__((address_space(1))) gc_t;
typedef unsigned char __attribute__((address_space(3))) lds_t;

__device__ __forceinline__ void gl_lds16(const void* g, void* l) {
    __builtin_amdgcn_global_load_lds((gc_t*)g, (lds_t*)l, 16, 0, 0);
}

// ------------------------------------------------------------ conversion
__global__ __launch_bounds__(256) void conv_x(
    const float* __restrict__ x, unsigned short* __restrict__ xb, int n4)
{
    int i = blockIdx.x * blockDim.x + threadIdx.x;
    if (i >= n4) return;
    float4 v = *(const float4*)(x + (long)i * 4);
    ushort4 o;
    o.x = f2bf(v.x); o.y = f2bf(v.y); o.z = f2bf(v.z); o.w = f2bf(v.w);
    *(ushort4*)(xb + (long)i * 4) = o;
}

// ------------------------------------------------------------ fused kernel
// Requires D == 256, U % 128 == 0, T % 64 == 0.
#define TC 64    // timesteps per chunk
#define GN 128   // units per block

__global__ __launch_bounds__(256, 1) void indrnn_fused(
    const unsigned short* __restrict__ xb,   // bf16 [B*T, 256]
    const float* __restrict__ W,             // fp32 [256, U]
    const float* __restrict__ bias,          // [U]
    const float* __restrict__ h0,            // [B, U]
    const float* __restrict__ uvec,          // [U]
    float* __restrict__ out,                 // [B, T, U]
    int B, int T, int U)
{
    __shared__ char Xs[2][TC * 512];         // 2 x 32 KB: bf16 A-chunks (dbuf)
    __shared__ char Ps[GN * TC * 4];         // 32 KB: fp32 proj, transposed [u][t]

    const int tid  = threadIdx.x;
    const int lane = tid & 63;
    const int w    = tid >> 6;     // wave 0..3
    const int m    = lane & 15;
    const int quad = lane >> 4;    // 0..3
    const int b    = blockIdx.x;
    const int n0   = blockIdx.y * GN;
    const int tq   = (w >> 1) * 32;   // wave's row quadrant (t-local)
    const int cq   = (w & 1) * 64;    // wave's col quadrant

    const unsigned short* xrow = xb + (long)b * T * 256;
    const int p  = lane & 31;
    const int hh = lane >> 5;

    // ---- prologue part 1: stage chunk 0 (all 4 waves, 8 x 1KB calls each).
    // LDS[row][pos] <- global granule (pos ^ (row&15))  [16B granules, 32/row]
#pragma unroll
    for (int i = 0; i < 8; ++i) {
        int blk = i * 4 + w;          // 1KB block = 2 rows
        int row = blk * 2 + hh;
        int gp  = p ^ (row & 15);
        gl_lds16(xrow + (long)row * 256 + gp * 8, &Xs[0][blk * 1024]);
    }

    // ---- prologue part 2 (overlaps DMA): W fragments from fp32 W.
    // bfr[j][kt][e] = bf16( W[(kt*32 + quad*8 + e)][n0 + cq + j*16 + m] ).
    bf16x8 bfr[4][8];
#pragma unroll
    for (int j = 0; j < 4; ++j)
#pragma unroll
        for (int kt = 0; kt < 8; ++kt) {
            const float* wp = W + (long)(kt * 32 + quad * 8) * U
                                + (n0 + cq + j * 16 + m);
            bf16x8 f;
#pragma unroll
            for (int e = 0; e < 8; ++e) f[e] = (__bf16)wp[(long)e * U];
            bfr[j][kt] = f;
        }

    float bb[4];
#pragma unroll
    for (int j = 0; j < 4; ++j) bb[j] = bias[n0 + cq + j * 16 + m];

    float uc = 0.0f, h = 0.0f;
    if (tid < GN) {
        uc = fminf(fmaxf(uvec[n0 + tid], 0.0f), 1.0f);
        h  = h0[(long)b * U + n0 + tid];
    }

    asm volatile("s_waitcnt vmcnt(0)" ::: "memory");
    __builtin_amdgcn_sched_barrier(0);
    __syncthreads();   // chunk 0 staged & visible

    const int nch = T / TC;
    for (int c = 0; c < nch; ++c) {
        const int buf = c & 1;

        // ---- issue staging of chunk c+1 into Xs[buf^1] FIRST: the DMA
        // overlaps this chunk's MFMA+proj+scan. Safe: Xs[buf^1] was last
        // read by MFMA(c-1), ordered by the tail barrier of c-1.
        if (c + 1 < nch) {
            const unsigned short* gb = xrow + (long)(c + 1) * TC * 256;
#pragma unroll
            for (int i = 0; i < 8; ++i) {
                int blk = i * 4 + w;
                int row = blk * 2 + hh;
                int gp  = p ^ (row & 15);
                gl_lds16(gb + (long)row * 256 + gp * 8, &Xs[buf ^ 1][blk * 1024]);
            }
        }

        // ---- MFMA: wave computes 32t x 64u quadrant; A bf16 from LDS,
        //      B-frags resident in VGPRs.
        f32x4 acc[2][4];
#pragma unroll
        for (int i = 0; i < 2; ++i)
#pragma unroll
            for (int j = 0; j < 4; ++j) acc[i][j] = (f32x4){0.f, 0.f, 0.f, 0.f};

#pragma unroll
        for (int kt = 0; kt < 8; ++kt) {
            const int off = (((kt * 4 + quad) ^ m) * 16);
            bf16x8 a0 = *(const bf16x8*)(&Xs[buf][(tq + m) * 512 + off]);
            bf16x8 a1 = *(const bf16x8*)(&Xs[buf][(tq + 16 + m) * 512 + off]);
#pragma unroll
            for (int j = 0; j < 4; ++j) {
                acc[0][j] = __builtin_amdgcn_mfma_f32_16x16x32_bf16(
                    a0, bfr[j][kt], acc[0][j], 0, 0, 0);
                acc[1][j] = __builtin_amdgcn_mfma_f32_16x16x32_bf16(
                    a1, bfr[j][kt], acc[1][j], 0, 0, 0);
            }
        }

        // ---- proj (+bias) -> P, transposed [u][t], 16B-granule XOR swizzle.
#pragma unroll
        for (int i = 0; i < 2; ++i)
#pragma unroll
            for (int j = 0; j < 4; ++j) {
                f32x4 v = acc[i][j];
                f32x4 vb = {v[0] + bb[j], v[1] + bb[j], v[2] + bb[j], v[3] + bb[j]};
                int col = cq + j * 16 + m;
                int g   = (tq >> 2) + i * 4 + quad;   // (t-row)>>2
                *(f32x4*)(Ps + col * 256 + (((g ^ (col & 7)) << 4))) = vb;
            }
        __syncthreads();   // proj visible to scan waves

        // ---- waves 0-1: sequential scan of chunk c from P (b128 reads)
        if (tid < GN) {
            f32x4 pv[16];
            const int ub = tid * 256;
            const int ux = (tid & 7) << 4;
#pragma unroll
            for (int gg = 0; gg < 16; ++gg)
                pv[gg] = *(const f32x4*)(Ps + ub + ((gg << 4) ^ ux));
            float* og = out + ((long)b * T + c * TC) * U + n0 + tid;
#pragma unroll
            for (int gg = 0; gg < 16; ++gg)
#pragma unroll
                for (int e = 0; e < 4; ++e) {
                    h = fmaxf(fmaf(h, uc, pv[gg][e]), 0.0f);
                    og[(long)(gg * 4 + e) * U] = h;
                }
        }

        // ---- counted tail drain (T4: never blanket vmcnt(0) in-loop).
        // Waves 0-1: queue = [<=48 old stores][8 gl_lds][64 new stores];
        //   waiting to <=48 outstanding retires everything older than the
        //   48 newest stores => all gl_lds retired; <=48 left (induction).
        // Waves 2-3: only the 8 gl_lds outstanding -> vmcnt(0).
        if (tid < GN) {
            asm volatile("s_waitcnt vmcnt(48)" ::: "memory");
        } else {
            asm volatile("s_waitcnt vmcnt(0)" ::: "memory");
        }
        __builtin_amdgcn_sched_barrier(0);
        __syncthreads();   // chunk c+1 staged; P free for next proj
    }
}

// ------------------------------------------------------------ fp32 fallback
#define BM 128
#define BN 128
#define BK 8

__global__ __launch_bounds__(256) void indrnn_gemm_bias(
    const float* __restrict__ A, const float* __restrict__ Bm,
    const float* __restrict__ bias, float* __restrict__ C,
    int M, int N, int K)
{
    __shared__ float As[BK][BM];
    __shared__ float Bs[BK][BN];
    const int tid = threadIdx.x;
    const int row0 = blockIdx.x * BM, col0 = blockIdx.y * BN;
    const int tx = tid & 15, ty = tid >> 4;
    float acc[8][8];
#pragma unroll
    for (int i = 0; i < 8; ++i)
#pragma unroll
        for (int j = 0; j < 8; ++j) acc[i][j] = 0.0f;
    const int am = tid >> 1, ak = (tid & 1) * 4;
    const int bk = tid >> 5, bn = (tid & 31) * 4;
    const float* Aptr = A + (long)(row0 + am) * K + ak;
    const float* Bptr = Bm + (long)bk * N + col0 + bn;
    for (int kt = 0; kt < K; kt += BK) {
        float4 av = *(const float4*)(Aptr + kt);
        float4 bv = *(const float4*)(Bptr + (long)kt * N);
        As[ak + 0][am] = av.x; As[ak + 1][am] = av.y;
        As[ak + 2][am] = av.z; As[ak + 3][am] = av.w;
        *(float4*)&Bs[bk][bn] = bv;
        __syncthreads();
#pragma unroll
        for (int k = 0; k < BK; ++k) {
            float4 a0 = *(const float4*)&As[k][ty * 4];
            float4 a1 = *(const float4*)&As[k][64 + ty * 4];
            float4 b0 = *(const float4*)&Bs[k][tx * 4];
            float4 b1 = *(const float4*)&Bs[k][64 + tx * 4];
            float a[8] = {a0.x, a0.y, a0.z, a0.w, a1.x, a1.y, a1.z, a1.w};
            float bb2[8] = {b0.x, b0.y, b0.z, b0.w, b1.x, b1.y, b1.z, b1.w};
#pragma unroll
            for (int i = 0; i < 8; ++i)
#pragma unroll
                for (int j = 0; j < 8; ++j)
                    acc[i][j] = fmaf(a[i], bb2[j], acc[i][j]);
        }
        __syncthreads();
    }
    float bb[8];
#pragma unroll
    for (int j = 0; j < 4; ++j) {
        bb[j] = bias[col0 + tx * 4 + j];
        bb[j + 4] = bias[col0 + 64 + tx * 4 + j];
    }
#pragma unroll
    for (int i = 0; i < 8; ++i) {
        const int r = (i < 4) ? (ty * 4 + i) : (64 + ty * 4 + (i - 4));
        float* crow = C + (long)(row0 + r) * N + col0;
        float4 v0 = {acc[i][0] + bb[0], acc[i][1] + bb[1], acc[i][2] + bb[2], acc[i][3] + bb[3]};
        float4 v1 = {acc[i][4] + bb[4], acc[i][5] + bb[5], acc[i][6] + bb[6], acc[i][7] + bb[7]};
        *(float4*)(crow + tx * 4) = v0;
        *(float4*)(crow + 64 + tx * 4) = v1;
    }
}

#define SCAN_UNROLL 32

__global__ __launch_bounds__(256) void indrnn_scan(
    float* __restrict__ out, const float* __restrict__ h0,
    const float* __restrict__ u, int B, int T, int U)
{
    const int idx = blockIdx.x * blockDim.x + threadIdx.x;
    if (idx >= B * U) return;
    const int b = idx / U;
    const int un = idx - b * U;
    const float uc = fminf(fmaxf(u[un], 0.0f), 1.0f);
    float h = h0[(long)b * U + un];
    float* p = out + (long)b * T * U + un;
    for (int t = 0; t < T; t += SCAN_UNROLL) {
        float pv[SCAN_UNROLL];
#pragma unroll
        for (int i = 0; i < SCAN_UNROLL; ++i)
            pv[i] = p[(long)(t + i) * U];
#pragma unroll
        for (int i = 0; i < SCAN_UNROLL; ++i) {
            h = fmaxf(fmaf(h, uc, pv[i]), 0.0f);
            pv[i] = h;
        }
#pragma unroll
        for (int i = 0; i < SCAN_UNROLL; ++i)
            p[(long)(t + i) * U] = pv[i];
    }
}

// ------------------------------------------------------------ launch
extern "C" void kernel_launch(void* const* d_in, const int* in_sizes, int n_in,
                              void* d_out, int out_size, void* d_ws, size_t ws_size,
                              hipStream_t stream) {
    const float* x  = (const float*)d_in[0]; // [B,T,D]
    const float* h0 = (const float*)d_in[1]; // [B,U]
    const float* W  = (const float*)d_in[2]; // [D,U]
    const float* u  = (const float*)d_in[3]; // [U]
    const float* b  = (const float*)d_in[4]; // [U]
    float* out = (float*)d_out;              // [B,T,U]

    const int U = in_sizes[3];
    const int B = in_sizes[1] / U;
    const int D = in_sizes[2] / U;
    const int T = in_sizes[0] / (B * D);
    const int M = B * T;

    const size_t xb_bytes = (size_t)M * D * sizeof(unsigned short);
    const bool fused_ok = (D == 256) && (U % GN == 0) && (T % TC == 0) &&
                          (ws_size >= xb_bytes);

    if (fused_ok) {
        unsigned short* xb = (unsigned short*)d_ws;
        const int n4 = (M * D) / 4;
        conv_x<<<(n4 + 255) / 256, 256, 0, stream>>>(x, xb, n4);

        dim3 g(B, U / GN);
        indrnn_fused<<<g, 256, 0, stream>>>(xb, W, b, h0, u, out, B, T, U);
    } else {
        dim3 ggrid(M / BM, U / BN);
        indrnn_gemm_bias<<<ggrid, 256, 0, stream>>>(x, W, b, out, M, U, D);
        const int nthreads = B * U;
        indrnn_scan<<<(nthreads + 255) / 256, 256, 0, stream>>>(out, h0, u, B, T, U);
    }
}